// Round 1
// baseline (262.986 us; speedup 1.0000x reference)
//
#include <hip/hip_runtime.h>

#define IN_FEAT 4096
#define OUT_FEAT 4096
#define RANK 1024
#define TOK 8192   // B*S = 4*2048

typedef _Float16 f16x8 __attribute__((ext_vector_type(8)));
typedef _Float16 f16x4 __attribute__((ext_vector_type(4)));
typedef float f32x4 __attribute__((ext_vector_type(4)));

#define GLD_LDS16(g, l)                                                         \
  __builtin_amdgcn_global_load_lds(                                             \
      (__attribute__((address_space(1))) const void*)(g),                       \
      (__attribute__((address_space(3))) void*)(l), 16, 0, 0)

// ---------------------------------------------------------------------------
// 2:4 soft-threshold sparsify, scale, cast to fp16.
// For each group of 4 along the last (rank) dim: t = 2nd smallest |g|;
// out = sign(g) * max(|g| - t, 0) * scale.
// ---------------------------------------------------------------------------

__device__ __forceinline__ void soft24(const float4 g, float s,
                                       float& r0, float& r1, float& r2, float& r3) {
  const float m0 = fabsf(g.x), m1 = fabsf(g.y), m2 = fabsf(g.z), m3 = fabsf(g.w);
  const float lo1 = fminf(m0, m1), hi1 = fmaxf(m0, m1);
  const float lo2 = fminf(m2, m3), hi2 = fmaxf(m2, m3);
  const float t = fminf(fmaxf(lo1, lo2), fminf(hi1, hi2));  // 2nd smallest
  r0 = copysignf(fmaxf(m0 - t, 0.0f), g.x) * s;
  r1 = copysignf(fmaxf(m1 - t, 0.0f), g.y) * s;
  r2 = copysignf(fmaxf(m2 - t, 0.0f), g.z) * s;
  r3 = copysignf(fmaxf(m3 - t, 0.0f), g.w) * s;
}

// weight_A (IN_FEAT x RANK) -> waT (RANK x IN_FEAT) fp16, transposed.
// Thread mapping: i (in index) fastest -> the 4 scalar fp16 stores are
// coalesced across the wave (consecutive i -> consecutive addresses).
__global__ __launch_bounds__(256) void sparsify_A_kernel(
    const float* __restrict__ wA, const float* __restrict__ scaleA,
    _Float16* __restrict__ waT) {
  const int idx = blockIdx.x * 256 + threadIdx.x;     // 0 .. IN*RANK/4
  const int i = idx & (IN_FEAT - 1);
  const int jg = idx >> 12;                           // rank group (of 4)
  const float4 g = *reinterpret_cast<const float4*>(wA + (size_t)i * RANK + jg * 4);
  const float s = scaleA[0];
  float r0, r1, r2, r3;
  soft24(g, s, r0, r1, r2, r3);
  const size_t base = (size_t)(jg * 4) * IN_FEAT + i;
  waT[base] = (_Float16)r0;
  waT[base + IN_FEAT] = (_Float16)r1;
  waT[base + 2 * IN_FEAT] = (_Float16)r2;
  waT[base + 3 * IN_FEAT] = (_Float16)r3;
}

// weight_B (OUT_FEAT x RANK) -> wbs (OUT_FEAT x RANK) fp16, same layout
// (already B^T form for GEMM2). Fully coalesced.
__global__ __launch_bounds__(256) void sparsify_B_kernel(
    const float* __restrict__ wB, const float* __restrict__ scaleB,
    _Float16* __restrict__ wbs) {
  const int idx = blockIdx.x * 256 + threadIdx.x;
  const float4 g = *reinterpret_cast<const float4*>(wB + (size_t)idx * 4);
  const float s = scaleB[0];
  float r0, r1, r2, r3;
  soft24(g, s, r0, r1, r2, r3);
  f16x4 h;
  h[0] = (_Float16)r0; h[1] = (_Float16)r1; h[2] = (_Float16)r2; h[3] = (_Float16)r3;
  *reinterpret_cast<f16x4*>(wbs + (size_t)idx * 4) = h;
}

// ---------------------------------------------------------------------------
// 128x128-tile MFMA GEMM, C = A * B^T (+bias), fp16 operands, fp32 accum.
//   A: M x K (fp32 if A_F32, cast to fp16 on staging; else fp16)
//   B: N x K fp16 (K contiguous = B^T input)
//   C: M x N (fp16 if OUT_F16, else fp32 + bias)
// BK=64, 4 waves (2x2), each wave 64x64 = 4x4 fragments of 16x16x32.
// LDS tiles [128][64] fp16 with 16B-granule XOR swizzle (u ^= row&7):
//   - fp16 staging: global_load_lds with pre-swizzled SOURCE, linear dest
//   - fp32 staging: reg-load + cvt + ds_write at swizzled dest
//   - ds_read_b128 applies the same XOR  -> no 16-way bank conflict
// ---------------------------------------------------------------------------
template <int N, int K, bool A_F32, bool OUT_F16>
__global__ __launch_bounds__(256, 2) void gemm128(
    const void* __restrict__ Av, const _Float16* __restrict__ Bh,
    void* __restrict__ Cv, const float* __restrict__ bias) {
  __shared__ __attribute__((aligned(128))) char lds[32768];
  char* ldsA = lds;
  char* ldsB = lds + 16384;

  const int tid = threadIdx.x;
  const int lane = tid & 63;
  const int w = tid >> 6;
  const int wrow = (w >> 1) * 64;
  const int wcol = (w & 1) * 64;
  const int brow = blockIdx.y * 128;
  const int bcol = blockIdx.x * 128;

  f32x4 acc[4][4] = {};

  for (int k0 = 0; k0 < K; k0 += 64) {
    __syncthreads();
    // ---- stage B tile: 128 rows x 64 halves, global_load_lds x4/thread ----
#pragma unroll
    for (int it = 0; it < 4; ++it) {
      const int c = it * 256 + tid;
      const int row = c >> 3;
      const int u = c & 7;
      const _Float16* gsrc =
          Bh + (size_t)(bcol + row) * K + k0 + ((u ^ (row & 7)) << 3);
      GLD_LDS16(gsrc, ldsB + c * 16);
    }
    // ---- stage A tile ----
    if constexpr (A_F32) {
      const float* Af = (const float*)Av;
#pragma unroll
      for (int it = 0; it < 4; ++it) {
        const int c = it * 256 + tid;
        const int row = c >> 3;
        const int u = c & 7;
        const float* gsrc = Af + (size_t)(brow + row) * K + k0 + (u << 3);
        const float4 f0 = *reinterpret_cast<const float4*>(gsrc);
        const float4 f1 = *reinterpret_cast<const float4*>(gsrc + 4);
        f16x8 h;
        h[0] = (_Float16)f0.x; h[1] = (_Float16)f0.y;
        h[2] = (_Float16)f0.z; h[3] = (_Float16)f0.w;
        h[4] = (_Float16)f1.x; h[5] = (_Float16)f1.y;
        h[6] = (_Float16)f1.z; h[7] = (_Float16)f1.w;
        *reinterpret_cast<f16x8*>(ldsA + row * 128 + ((u ^ (row & 7)) << 4)) = h;
      }
    } else {
      const _Float16* Ah = (const _Float16*)Av;
#pragma unroll
      for (int it = 0; it < 4; ++it) {
        const int c = it * 256 + tid;
        const int row = c >> 3;
        const int u = c & 7;
        const _Float16* gsrc =
            Ah + (size_t)(brow + row) * K + k0 + ((u ^ (row & 7)) << 3);
        GLD_LDS16(gsrc, ldsA + c * 16);
      }
    }
    __syncthreads();
    // ---- compute: 2 k-chunks x 16 MFMA ----
#pragma unroll
    for (int kk = 0; kk < 2; ++kk) {
      f16x8 af[4], bf[4];
#pragma unroll
      for (int m = 0; m < 4; ++m) {
        const int row = wrow + m * 16 + (lane & 15);
        const int u = (kk * 4 + (lane >> 4)) ^ (row & 7);
        af[m] = *reinterpret_cast<const f16x8*>(ldsA + row * 128 + u * 16);
      }
#pragma unroll
      for (int n = 0; n < 4; ++n) {
        const int row = wcol + n * 16 + (lane & 15);
        const int u = (kk * 4 + (lane >> 4)) ^ (row & 7);
        bf[n] = *reinterpret_cast<const f16x8*>(ldsB + row * 128 + u * 16);
      }
#pragma unroll
      for (int m = 0; m < 4; ++m)
#pragma unroll
        for (int n = 0; n < 4; ++n)
          acc[m][n] =
              __builtin_amdgcn_mfma_f32_16x16x32_f16(af[m], bf[n], acc[m][n], 0, 0, 0);
    }
  }

  // ---- epilogue: C/D layout col = lane&15, row = (lane>>4)*4 + j ----
  const int r4 = (lane >> 4) * 4;
  const int cl = lane & 15;
  if constexpr (OUT_F16) {
    _Float16* C = (_Float16*)Cv;
#pragma unroll
    for (int m = 0; m < 4; ++m)
#pragma unroll
      for (int n = 0; n < 4; ++n)
#pragma unroll
        for (int j = 0; j < 4; ++j) {
          const int rr = brow + wrow + m * 16 + r4 + j;
          const int cc = bcol + wcol + n * 16 + cl;
          C[(size_t)rr * N + cc] = (_Float16)acc[m][n][j];
        }
  } else {
    float* C = (float*)Cv;
#pragma unroll
    for (int n = 0; n < 4; ++n) {
      const int cc = bcol + wcol + n * 16 + cl;
      const float bv = bias[cc];
#pragma unroll
      for (int m = 0; m < 4; ++m)
#pragma unroll
        for (int j = 0; j < 4; ++j) {
          const int rr = brow + wrow + m * 16 + r4 + j;
          C[(size_t)rr * N + cc] = acc[m][n][j] + bv;
        }
    }
  }
}

// ---------------------------------------------------------------------------

extern "C" void kernel_launch(void* const* d_in, const int* in_sizes, int n_in,
                              void* d_out, int out_size, void* d_ws, size_t ws_size,
                              hipStream_t stream) {
  const float* x = (const float*)d_in[0];       // (TOK, IN_FEAT)
  const float* wA = (const float*)d_in[1];      // (IN_FEAT, RANK)
  const float* wB = (const float*)d_in[2];      // (OUT_FEAT, RANK)
  const float* bias = (const float*)d_in[3];    // (OUT_FEAT)
  const float* scaleA = (const float*)d_in[4];  // scalar
  const float* scaleB = (const float*)d_in[5];  // scalar
  float* out = (float*)d_out;                   // (TOK, OUT_FEAT)

  char* ws = (char*)d_ws;
  _Float16* waT = (_Float16*)ws;  // RANK x IN_FEAT (8 MB)
  _Float16* wbs = (_Float16*)(ws + (size_t)RANK * IN_FEAT * 2);  // OUT_FEAT x RANK (8 MB)
  _Float16* xp =
      (_Float16*)(ws + (size_t)RANK * IN_FEAT * 2 + (size_t)OUT_FEAT * RANK * 2);  // TOK x RANK (16 MB)

  hipLaunchKernelGGL(sparsify_A_kernel, dim3((IN_FEAT * RANK / 4) / 256), dim3(256),
                     0, stream, wA, scaleA, waT);
  hipLaunchKernelGGL(sparsify_B_kernel, dim3((OUT_FEAT * RANK / 4) / 256), dim3(256),
                     0, stream, wB, scaleB, wbs);

  // GEMM1: x_proj(fp16) = cast16(x) @ waT^T   (M=TOK, N=RANK, K=IN_FEAT)
  hipLaunchKernelGGL((gemm128<RANK, IN_FEAT, true, true>),
                     dim3(RANK / 128, TOK / 128), dim3(256), 0, stream,
                     (const void*)x, waT, (void*)xp, nullptr);

  // GEMM2: out(fp32) = x_proj @ wbs^T + bias  (M=TOK, N=OUT_FEAT, K=RANK)
  hipLaunchKernelGGL((gemm128<OUT_FEAT, RANK, false, false>),
                     dim3(OUT_FEAT / 128, TOK / 128), dim3(256), 0, stream,
                     (const void*)xp, wbs, (void*)out, bias);
}

// Round 2
// 214.002 us; speedup vs baseline: 1.2289x; 1.2289x over previous
//
#include <hip/hip_runtime.h>

#define IN_FEAT 4096
#define OUT_FEAT 4096
#define RANK 1024
#define TOK 8192   // B*S = 4*2048

typedef _Float16 f16x8 __attribute__((ext_vector_type(8)));
typedef _Float16 f16x4 __attribute__((ext_vector_type(4)));
typedef float f32x4 __attribute__((ext_vector_type(4)));

#define GLD_LDS16(g, l)                                                         \
  __builtin_amdgcn_global_load_lds(                                             \
      (__attribute__((address_space(1))) const void*)(g),                       \
      (__attribute__((address_space(3))) void*)(l), 16, 0, 0)

// ---------------------------------------------------------------------------
// 2:4 soft-threshold sparsify, scale, cast to fp16.
// ---------------------------------------------------------------------------

__device__ __forceinline__ void soft24(const float4 g, float s,
                                       float& r0, float& r1, float& r2, float& r3) {
  const float m0 = fabsf(g.x), m1 = fabsf(g.y), m2 = fabsf(g.z), m3 = fabsf(g.w);
  const float lo1 = fminf(m0, m1), hi1 = fmaxf(m0, m1);
  const float lo2 = fminf(m2, m3), hi2 = fmaxf(m2, m3);
  const float t = fminf(fmaxf(lo1, lo2), fminf(hi1, hi2));  // 2nd smallest
  r0 = copysignf(fmaxf(m0 - t, 0.0f), g.x) * s;
  r1 = copysignf(fmaxf(m1 - t, 0.0f), g.y) * s;
  r2 = copysignf(fmaxf(m2 - t, 0.0f), g.z) * s;
  r3 = copysignf(fmaxf(m3 - t, 0.0f), g.w) * s;
}

// weight_A (IN_FEAT x RANK) -> waT (RANK x IN_FEAT) fp16, transposed.
__global__ __launch_bounds__(256) void sparsify_A_kernel(
    const float* __restrict__ wA, const float* __restrict__ scaleA,
    _Float16* __restrict__ waT) {
  const int idx = blockIdx.x * 256 + threadIdx.x;     // 0 .. IN*RANK/4
  const int i = idx & (IN_FEAT - 1);
  const int jg = idx >> 12;                           // rank group (of 4)
  const float4 g = *reinterpret_cast<const float4*>(wA + (size_t)i * RANK + jg * 4);
  const float s = scaleA[0];
  float r0, r1, r2, r3;
  soft24(g, s, r0, r1, r2, r3);
  const size_t base = (size_t)(jg * 4) * IN_FEAT + i;
  waT[base] = (_Float16)r0;
  waT[base + IN_FEAT] = (_Float16)r1;
  waT[base + 2 * IN_FEAT] = (_Float16)r2;
  waT[base + 3 * IN_FEAT] = (_Float16)r3;
}

// weight_B (OUT_FEAT x RANK) -> wbs (OUT_FEAT x RANK) fp16 (already B^T form).
__global__ __launch_bounds__(256) void sparsify_B_kernel(
    const float* __restrict__ wB, const float* __restrict__ scaleB,
    _Float16* __restrict__ wbs) {
  const int idx = blockIdx.x * 256 + threadIdx.x;
  const float4 g = *reinterpret_cast<const float4*>(wB + (size_t)idx * 4);
  const float s = scaleB[0];
  float r0, r1, r2, r3;
  soft24(g, s, r0, r1, r2, r3);
  f16x4 h;
  h[0] = (_Float16)r0; h[1] = (_Float16)r1; h[2] = (_Float16)r2; h[3] = (_Float16)r3;
  *reinterpret_cast<f16x4*>(wbs + (size_t)idx * 4) = h;
}

// x (fp32) -> x16 (fp16), 8 elems/thread, fully coalesced.
__global__ __launch_bounds__(256) void cast_x_kernel(
    const float* __restrict__ x, _Float16* __restrict__ x16) {
  const size_t i = ((size_t)blockIdx.x * 256 + threadIdx.x) * 8;
  const float4 f0 = *reinterpret_cast<const float4*>(x + i);
  const float4 f1 = *reinterpret_cast<const float4*>(x + i + 4);
  f16x8 h;
  h[0] = (_Float16)f0.x; h[1] = (_Float16)f0.y;
  h[2] = (_Float16)f0.z; h[3] = (_Float16)f0.w;
  h[4] = (_Float16)f1.x; h[5] = (_Float16)f1.y;
  h[6] = (_Float16)f1.z; h[7] = (_Float16)f1.w;
  *reinterpret_cast<f16x8*>(x16 + i) = h;
}

// ---------------------------------------------------------------------------
// 128x128-tile MFMA GEMM, C = A * B^T (+bias), fp16 operands, fp32 accum.
//   A: M x K (fp32 if A_F32 -> reg-stage+cvt; else fp16 -> global_load_lds)
//   B: N x K fp16 (K contiguous = B^T input), global_load_lds
//   C: M x N (fp16 if OUT_F16, else fp32 + bias)
// LDS tiles [128][64] fp16 with 16B-granule XOR swizzle (u ^= row&7).
// XCD-aware bijective swizzle: the GX column-blocks sharing one A row-panel
// land on the same XCD (consecutive logical wg ids -> same chiplet L2).
// ---------------------------------------------------------------------------
template <int N, int K, bool A_F32, bool OUT_F16>
__global__ __launch_bounds__(256, 4) void gemm128(
    const void* __restrict__ Av, const _Float16* __restrict__ Bh,
    void* __restrict__ Cv, const float* __restrict__ bias) {
  __shared__ __attribute__((aligned(128))) char lds[32768];
  char* ldsA = lds;
  char* ldsB = lds + 16384;

  const int tid = threadIdx.x;
  const int lane = tid & 63;
  const int w = tid >> 6;
  const int wrow = (w >> 1) * 64;
  const int wcol = (w & 1) * 64;

  // XCD swizzle (nwg % 8 == 0 for all our grids)
  constexpr int GX = N / 128;
  const int nwg = GX * (TOK / 128);
  const int l = blockIdx.y * GX + blockIdx.x;
  const int wg = (l & 7) * (nwg >> 3) + (l >> 3);
  const int brow = (wg / GX) * 128;
  const int bcol = (wg % GX) * 128;

  f32x4 acc[4][4] = {};

  for (int k0 = 0; k0 < K; k0 += 64) {
    __syncthreads();
    // ---- stage B tile ----
#pragma unroll
    for (int it = 0; it < 4; ++it) {
      const int c = it * 256 + tid;
      const int row = c >> 3;
      const int u = c & 7;
      const _Float16* gsrc =
          Bh + (size_t)(bcol + row) * K + k0 + ((u ^ (row & 7)) << 3);
      GLD_LDS16(gsrc, ldsB + c * 16);
    }
    // ---- stage A tile ----
    if constexpr (A_F32) {
      const float* Af = (const float*)Av;
#pragma unroll
      for (int it = 0; it < 4; ++it) {
        const int c = it * 256 + tid;
        const int row = c >> 3;
        const int u = c & 7;
        const float* gsrc = Af + (size_t)(brow + row) * K + k0 + (u << 3);
        const float4 f0 = *reinterpret_cast<const float4*>(gsrc);
        const float4 f1 = *reinterpret_cast<const float4*>(gsrc + 4);
        f16x8 h;
        h[0] = (_Float16)f0.x; h[1] = (_Float16)f0.y;
        h[2] = (_Float16)f0.z; h[3] = (_Float16)f0.w;
        h[4] = (_Float16)f1.x; h[5] = (_Float16)f1.y;
        h[6] = (_Float16)f1.z; h[7] = (_Float16)f1.w;
        *reinterpret_cast<f16x8*>(ldsA + row * 128 + ((u ^ (row & 7)) << 4)) = h;
      }
    } else {
      const _Float16* Ah = (const _Float16*)Av;
#pragma unroll
      for (int it = 0; it < 4; ++it) {
        const int c = it * 256 + tid;
        const int row = c >> 3;
        const int u = c & 7;
        const _Float16* gsrc =
            Ah + (size_t)(brow + row) * K + k0 + ((u ^ (row & 7)) << 3);
        GLD_LDS16(gsrc, ldsA + c * 16);
      }
    }
    __syncthreads();
    // ---- compute: 2 k-chunks x 16 MFMA ----
#pragma unroll
    for (int kk = 0; kk < 2; ++kk) {
      f16x8 af[4], bf[4];
#pragma unroll
      for (int m = 0; m < 4; ++m) {
        const int row = wrow + m * 16 + (lane & 15);
        const int u = (kk * 4 + (lane >> 4)) ^ (row & 7);
        af[m] = *reinterpret_cast<const f16x8*>(ldsA + row * 128 + u * 16);
      }
#pragma unroll
      for (int n = 0; n < 4; ++n) {
        const int row = wcol + n * 16 + (lane & 15);
        const int u = (kk * 4 + (lane >> 4)) ^ (row & 7);
        bf[n] = *reinterpret_cast<const f16x8*>(ldsB + row * 128 + u * 16);
      }
#pragma unroll
      for (int m = 0; m < 4; ++m)
#pragma unroll
        for (int n = 0; n < 4; ++n)
          acc[m][n] =
              __builtin_amdgcn_mfma_f32_16x16x32_f16(af[m], bf[n], acc[m][n], 0, 0, 0);
    }
  }

  // ---- epilogue: C/D layout col = lane&15, row = (lane>>4)*4 + j ----
  const int r4 = (lane >> 4) * 4;
  const int cl = lane & 15;
  if constexpr (OUT_F16) {
    _Float16* C = (_Float16*)Cv;
#pragma unroll
    for (int m = 0; m < 4; ++m)
#pragma unroll
      for (int n = 0; n < 4; ++n)
#pragma unroll
        for (int j = 0; j < 4; ++j) {
          const int rr = brow + wrow + m * 16 + r4 + j;
          const int cc = bcol + wcol + n * 16 + cl;
          C[(size_t)rr * N + cc] = (_Float16)acc[m][n][j];
        }
  } else {
    float* C = (float*)Cv;
#pragma unroll
    for (int n = 0; n < 4; ++n) {
      const int cc = bcol + wcol + n * 16 + cl;
      const float bv = bias[cc];
#pragma unroll
      for (int m = 0; m < 4; ++m)
#pragma unroll
        for (int j = 0; j < 4; ++j) {
          const int rr = brow + wrow + m * 16 + r4 + j;
          C[(size_t)rr * N + cc] = acc[m][n][j] + bv;
        }
    }
  }
}

// ---------------------------------------------------------------------------

extern "C" void kernel_launch(void* const* d_in, const int* in_sizes, int n_in,
                              void* d_out, int out_size, void* d_ws, size_t ws_size,
                              hipStream_t stream) {
  const float* x = (const float*)d_in[0];       // (TOK, IN_FEAT)
  const float* wA = (const float*)d_in[1];      // (IN_FEAT, RANK)
  const float* wB = (const float*)d_in[2];      // (OUT_FEAT, RANK)
  const float* bias = (const float*)d_in[3];    // (OUT_FEAT)
  const float* scaleA = (const float*)d_in[4];  // scalar
  const float* scaleB = (const float*)d_in[5];  // scalar
  float* out = (float*)d_out;                   // (TOK, OUT_FEAT)

  char* ws = (char*)d_ws;
  _Float16* waT = (_Float16*)ws;                                  // 8 MB
  _Float16* wbs = (_Float16*)(ws + (size_t)RANK * IN_FEAT * 2);   // 8 MB
  _Float16* xp =
      (_Float16*)(ws + (size_t)RANK * IN_FEAT * 2 + (size_t)OUT_FEAT * RANK * 2);  // 16 MB
  _Float16* x16 = (_Float16*)(ws + (size_t)RANK * IN_FEAT * 2 +
                              (size_t)OUT_FEAT * RANK * 2 + (size_t)TOK * RANK * 2);  // 64 MB
  const size_t needed = (size_t)RANK * IN_FEAT * 2 + (size_t)OUT_FEAT * RANK * 2 +
                        (size_t)TOK * RANK * 2 + (size_t)TOK * IN_FEAT * 2;

  hipLaunchKernelGGL(sparsify_A_kernel, dim3((IN_FEAT * RANK / 4) / 256), dim3(256),
                     0, stream, wA, scaleA, waT);
  hipLaunchKernelGGL(sparsify_B_kernel, dim3((OUT_FEAT * RANK / 4) / 256), dim3(256),
                     0, stream, wB, scaleB, wbs);

  if (ws_size >= needed) {
    // cast x once, then both GEMMs are pure-fp16 global_load_lds staged
    hipLaunchKernelGGL(cast_x_kernel, dim3((TOK * IN_FEAT / 8) / 256), dim3(256),
                       0, stream, x, x16);
    hipLaunchKernelGGL((gemm128<RANK, IN_FEAT, false, true>),
                       dim3(RANK / 128, TOK / 128), dim3(256), 0, stream,
                       (const void*)x16, waT, (void*)xp, nullptr);
  } else {
    hipLaunchKernelGGL((gemm128<RANK, IN_FEAT, true, true>),
                       dim3(RANK / 128, TOK / 128), dim3(256), 0, stream,
                       (const void*)x, waT, (void*)xp, nullptr);
  }

  // GEMM2: out(fp32) = x_proj @ wbs^T + bias  (M=TOK, N=OUT_FEAT, K=RANK)
  hipLaunchKernelGGL((gemm128<OUT_FEAT, RANK, false, false>),
                     dim3(OUT_FEAT / 128, TOK / 128), dim3(256), 0, stream,
                     (const void*)xp, wbs, (void*)out, bias);
}

// Round 3
// 206.191 us; speedup vs baseline: 1.2754x; 1.0379x over previous
//
#include <hip/hip_runtime.h>

#define IN_FEAT 4096
#define OUT_FEAT 4096
#define RANK 1024
#define TOK 8192   // B*S = 4*2048

typedef _Float16 f16x8 __attribute__((ext_vector_type(8)));
typedef _Float16 f16x4 __attribute__((ext_vector_type(4)));
typedef float f32x4 __attribute__((ext_vector_type(4)));

#define GLD_LDS16(g, l)                                                         \
  __builtin_amdgcn_global_load_lds(                                             \
      (__attribute__((address_space(1))) const void*)(g),                       \
      (__attribute__((address_space(3))) void*)(l), 16, 0, 0)

// ---------------------------------------------------------------------------
// 2:4 soft-threshold sparsify, scale, cast to fp16.
// ---------------------------------------------------------------------------

__device__ __forceinline__ void soft24(const float4 g, float s,
                                       float& r0, float& r1, float& r2, float& r3) {
  const float m0 = fabsf(g.x), m1 = fabsf(g.y), m2 = fabsf(g.z), m3 = fabsf(g.w);
  const float lo1 = fminf(m0, m1), hi1 = fmaxf(m0, m1);
  const float lo2 = fminf(m2, m3), hi2 = fmaxf(m2, m3);
  const float t = fminf(fmaxf(lo1, lo2), fminf(hi1, hi2));  // 2nd smallest
  r0 = copysignf(fmaxf(m0 - t, 0.0f), g.x) * s;
  r1 = copysignf(fmaxf(m1 - t, 0.0f), g.y) * s;
  r2 = copysignf(fmaxf(m2 - t, 0.0f), g.z) * s;
  r3 = copysignf(fmaxf(m3 - t, 0.0f), g.w) * s;
}

__global__ __launch_bounds__(256) void sparsify_A_kernel(
    const float* __restrict__ wA, const float* __restrict__ scaleA,
    _Float16* __restrict__ waT) {
  const int idx = blockIdx.x * 256 + threadIdx.x;
  const int i = idx & (IN_FEAT - 1);
  const int jg = idx >> 12;
  const float4 g = *reinterpret_cast<const float4*>(wA + (size_t)i * RANK + jg * 4);
  const float s = scaleA[0];
  float r0, r1, r2, r3;
  soft24(g, s, r0, r1, r2, r3);
  const size_t base = (size_t)(jg * 4) * IN_FEAT + i;
  waT[base] = (_Float16)r0;
  waT[base + IN_FEAT] = (_Float16)r1;
  waT[base + 2 * IN_FEAT] = (_Float16)r2;
  waT[base + 3 * IN_FEAT] = (_Float16)r3;
}

__global__ __launch_bounds__(256) void sparsify_B_kernel(
    const float* __restrict__ wB, const float* __restrict__ scaleB,
    _Float16* __restrict__ wbs) {
  const int idx = blockIdx.x * 256 + threadIdx.x;
  const float4 g = *reinterpret_cast<const float4*>(wB + (size_t)idx * 4);
  const float s = scaleB[0];
  float r0, r1, r2, r3;
  soft24(g, s, r0, r1, r2, r3);
  f16x4 h;
  h[0] = (_Float16)r0; h[1] = (_Float16)r1; h[2] = (_Float16)r2; h[3] = (_Float16)r3;
  *reinterpret_cast<f16x4*>(wbs + (size_t)idx * 4) = h;
}

__global__ __launch_bounds__(256) void cast_x_kernel(
    const float* __restrict__ x, _Float16* __restrict__ x16) {
  const size_t i = ((size_t)blockIdx.x * 256 + threadIdx.x) * 8;
  const float4 f0 = *reinterpret_cast<const float4*>(x + i);
  const float4 f1 = *reinterpret_cast<const float4*>(x + i + 4);
  f16x8 h;
  h[0] = (_Float16)f0.x; h[1] = (_Float16)f0.y;
  h[2] = (_Float16)f0.z; h[3] = (_Float16)f0.w;
  h[4] = (_Float16)f1.x; h[5] = (_Float16)f1.y;
  h[6] = (_Float16)f1.z; h[7] = (_Float16)f1.w;
  *reinterpret_cast<f16x8*>(x16 + i) = h;
}

// ---------------------------------------------------------------------------
// 128x128-tile GEMM (verified R1/R2) — used for GEMM1.
// ---------------------------------------------------------------------------
template <int N, int K, bool A_F32, bool OUT_F16>
__global__ __launch_bounds__(256, 4) void gemm128(
    const void* __restrict__ Av, const _Float16* __restrict__ Bh,
    void* __restrict__ Cv, const float* __restrict__ bias) {
  __shared__ __attribute__((aligned(128))) char lds[32768];
  char* ldsA = lds;
  char* ldsB = lds + 16384;

  const int tid = threadIdx.x;
  const int lane = tid & 63;
  const int w = tid >> 6;
  const int wrow = (w >> 1) * 64;
  const int wcol = (w & 1) * 64;

  constexpr int GX = N / 128;
  const int nwg = GX * (TOK / 128);
  const int l = blockIdx.y * GX + blockIdx.x;
  const int wg = (l & 7) * (nwg >> 3) + (l >> 3);
  const int brow = (wg / GX) * 128;
  const int bcol = (wg % GX) * 128;

  f32x4 acc[4][4] = {};

  for (int k0 = 0; k0 < K; k0 += 64) {
    __syncthreads();
#pragma unroll
    for (int it = 0; it < 4; ++it) {
      const int c = it * 256 + tid;
      const int row = c >> 3;
      const int u = c & 7;
      const _Float16* gsrc =
          Bh + (size_t)(bcol + row) * K + k0 + ((u ^ (row & 7)) << 3);
      GLD_LDS16(gsrc, ldsB + c * 16);
    }
    if constexpr (A_F32) {
      const float* Af = (const float*)Av;
#pragma unroll
      for (int it = 0; it < 4; ++it) {
        const int c = it * 256 + tid;
        const int row = c >> 3;
        const int u = c & 7;
        const float* gsrc = Af + (size_t)(brow + row) * K + k0 + (u << 3);
        const float4 f0 = *reinterpret_cast<const float4*>(gsrc);
        const float4 f1 = *reinterpret_cast<const float4*>(gsrc + 4);
        f16x8 h;
        h[0] = (_Float16)f0.x; h[1] = (_Float16)f0.y;
        h[2] = (_Float16)f0.z; h[3] = (_Float16)f0.w;
        h[4] = (_Float16)f1.x; h[5] = (_Float16)f1.y;
        h[6] = (_Float16)f1.z; h[7] = (_Float16)f1.w;
        *reinterpret_cast<f16x8*>(ldsA + row * 128 + ((u ^ (row & 7)) << 4)) = h;
      }
    } else {
      const _Float16* Ah = (const _Float16*)Av;
#pragma unroll
      for (int it = 0; it < 4; ++it) {
        const int c = it * 256 + tid;
        const int row = c >> 3;
        const int u = c & 7;
        const _Float16* gsrc =
            Ah + (size_t)(brow + row) * K + k0 + ((u ^ (row & 7)) << 3);
        GLD_LDS16(gsrc, ldsA + c * 16);
      }
    }
    __syncthreads();
#pragma unroll
    for (int kk = 0; kk < 2; ++kk) {
      f16x8 af[4], bf[4];
#pragma unroll
      for (int m = 0; m < 4; ++m) {
        const int row = wrow + m * 16 + (lane & 15);
        const int u = (kk * 4 + (lane >> 4)) ^ (row & 7);
        af[m] = *reinterpret_cast<const f16x8*>(ldsA + row * 128 + u * 16);
      }
#pragma unroll
      for (int n = 0; n < 4; ++n) {
        const int row = wcol + n * 16 + (lane & 15);
        const int u = (kk * 4 + (lane >> 4)) ^ (row & 7);
        bf[n] = *reinterpret_cast<const f16x8*>(ldsB + row * 128 + u * 16);
      }
#pragma unroll
      for (int m = 0; m < 4; ++m)
#pragma unroll
        for (int n = 0; n < 4; ++n)
          acc[m][n] =
              __builtin_amdgcn_mfma_f32_16x16x32_f16(af[m], bf[n], acc[m][n], 0, 0, 0);
    }
  }

  const int r4 = (lane >> 4) * 4;
  const int cl = lane & 15;
  if constexpr (OUT_F16) {
    _Float16* C = (_Float16*)Cv;
#pragma unroll
    for (int m = 0; m < 4; ++m)
#pragma unroll
      for (int n = 0; n < 4; ++n)
#pragma unroll
        for (int j = 0; j < 4; ++j) {
          const int rr = brow + wrow + m * 16 + r4 + j;
          const int cc = bcol + wcol + n * 16 + cl;
          C[(size_t)rr * N + cc] = (_Float16)acc[m][n][j];
        }
  } else {
    float* C = (float*)Cv;
#pragma unroll
    for (int n = 0; n < 4; ++n) {
      const int cc = bcol + wcol + n * 16 + cl;
      const float bv = bias[cc];
#pragma unroll
      for (int m = 0; m < 4; ++m)
#pragma unroll
        for (int j = 0; j < 4; ++j) {
          const int rr = brow + wrow + m * 16 + r4 + j;
          C[(size_t)rr * N + cc] = acc[m][n][j] + bv;
        }
    }
  }
}

// ---------------------------------------------------------------------------
// 256x256 8-phase GEMM (T2+T3+T4+T5), C(f32) = A(f16,MxK) @ B(f16,NxK)^T + bias
// 8 waves (2Mx4N), per-wave 128x64 output, BK=64, 2 K-tiles/iter.
// LDS (128 KiB dynamic): A/B x slot{0,1} x half{0,1}, 16 KiB buffers.
// Phase roles per K-tile: q0 reads A[m0-3]+B[n0-1]; q1 B[n2-3]; q2 A[m4-7]; q3 -.
// Stage 1 half-tile/phase: ph1-2 A(t+1), ph3-4 B(t+2), ph5-6 A(t+2), ph7-8 B(t+3).
// Each stage targets a buffer whose last ds_read was >=1 end-barrier earlier.
// vmcnt(4) at ph4/ph8 only (counted, never 0 in steady loop).
// ---------------------------------------------------------------------------
#define AOFF(s, h) (((s) * 2 + (h)) * 16384)
#define BOFF(s, h) (65536 + ((s) * 2 + (h)) * 16384)

#define MIDBAR()                                        \
  __builtin_amdgcn_s_barrier();                         \
  asm volatile("s_waitcnt lgkmcnt(0)" ::: "memory")
#define ENDBAR() __builtin_amdgcn_s_barrier()

#define QUAD(AF, BF, MO, NO)                                                   \
  __builtin_amdgcn_s_setprio(1);                                               \
  _Pragma("unroll") for (int ks = 0; ks < 2; ++ks)                             \
  _Pragma("unroll") for (int i = 0; i < 4; ++i)                                \
  _Pragma("unroll") for (int j = 0; j < 2; ++j)                                \
      acc[(MO) + i][(NO) + j] = __builtin_amdgcn_mfma_f32_16x16x32_f16(        \
          AF[i][ks], BF[j][ks], acc[(MO) + i][(NO) + j], 0, 0, 0);             \
  __builtin_amdgcn_s_setprio(0);

template <int M, int N, int K>
__global__ __launch_bounds__(512, 2) void gemm256(
    const _Float16* __restrict__ A, const _Float16* __restrict__ B,
    float* __restrict__ C, const float* __restrict__ bias) {
  extern __shared__ char lds[];

  const int tid = threadIdx.x;
  const int lane = tid & 63;
  const int w = tid >> 6;
  const int wr = w >> 2;  // 0..1
  const int wc = w & 3;   // 0..3
  const int l15 = lane & 15;
  const int ubase = lane >> 4;

  constexpr int GX = N / 256;
  constexpr int NWG = GX * (M / 256);
  const int l = blockIdx.y * GX + blockIdx.x;
  const int wg = (l & 7) * (NWG >> 3) + (l >> 3);
  const int brow = (wg / GX) * 256;
  const int bcol = (wg % GX) * 256;

  const _Float16* Abase = A + (size_t)brow * K;
  const _Float16* Bbase = B + (size_t)bcol * K;

  // stage one 128x64 half-tile (2 global_load_lds rounds, pre-swizzled src,
  // linear LDS dest)
  auto stage = [&](const _Float16* srcBase, int rowOff, int kof, int ldsOff) {
#pragma unroll
    for (int r = 0; r < 2; ++r) {
      const int c = r * 512 + tid;
      const int row = c >> 3;
      const int u = c & 7;
      const _Float16* g =
          srcBase + (size_t)(rowOff + row) * K + kof + ((u ^ (row & 7)) << 3);
      GLD_LDS16(g, lds + ldsOff + c * 16);
    }
  };

  f32x4 acc[8][4] = {};
  f16x8 af[4][2], bf01[2][2], bf23[2][2];

#define LDA_GRP(SLOT, MBASE)                                                   \
  _Pragma("unroll") for (int i = 0; i < 4; ++i)                                \
  _Pragma("unroll") for (int ks = 0; ks < 2; ++ks) {                           \
    const int row = ((MBASE) + i) * 16 + l15;                                  \
    const int u = (ks * 4 + ubase) ^ (row & 7);                                \
    af[i][ks] = *reinterpret_cast<const f16x8*>(                               \
        lds + AOFF(SLOT, wr) + row * 128 + u * 16);                            \
  }
#define LDB_GRP(SLOT, NBASE, DST)                                              \
  _Pragma("unroll") for (int j = 0; j < 2; ++j)                                \
  _Pragma("unroll") for (int ks = 0; ks < 2; ++ks) {                           \
    const int row = (wc & 1) * 64 + ((NBASE) + j) * 16 + l15;                  \
    const int u = (ks * 4 + ubase) ^ (row & 7);                                \
    DST[j][ks] = *reinterpret_cast<const f16x8*>(                              \
        lds + BOFF(SLOT, wc >> 1) + row * 128 + u * 16);                       \
  }

  constexpr int NT = K / 64;  // K-tiles (even, >= 2)

  // ---- prologue: stage A(0), B(0), B(1); require A(0),B(0) landed ----
  stage(Abase, 0, 0, AOFF(0, 0));
  stage(Abase, 128, 0, AOFF(0, 1));
  stage(Bbase, 0, 0, BOFF(0, 0));
  stage(Bbase, 128, 0, BOFF(0, 1));
  stage(Bbase, 0, 64, BOFF(1, 0));
  stage(Bbase, 128, 64, BOFF(1, 1));
  asm volatile("s_waitcnt vmcnt(4)" ::: "memory");
  __builtin_amdgcn_s_barrier();

  for (int tt = 0; tt < NT; tt += 2) {
    const bool last = (tt + 2 >= NT);
    const int kof1 = tt * 64 + 64;   // K-tile t+1
    const int kof2 = tt * 64 + 128;  // t+2
    const int kof3 = tt * 64 + 192;  // t+3

    // ---- PH1: (t,q0) ----
    LDA_GRP(0, 0);
    LDB_GRP(0, 0, bf01);
    stage(Abase, 0, kof1, AOFF(1, 0));
    MIDBAR();
    QUAD(af, bf01, 0, 0);
    ENDBAR();
    // ---- PH2: (t,q1) ----
    LDB_GRP(0, 2, bf23);
    stage(Abase, 128, kof1, AOFF(1, 1));
    MIDBAR();
    QUAD(af, bf23, 0, 2);
    ENDBAR();
    // ---- PH3: (t,q2) ----
    LDA_GRP(0, 4);
    if (!last) stage(Bbase, 0, kof2, BOFF(0, 0));
    MIDBAR();
    QUAD(af, bf01, 4, 0);
    ENDBAR();
    // ---- PH4: (t,q3) ----
    if (!last) {
      stage(Bbase, 128, kof2, BOFF(0, 1));
      asm volatile("s_waitcnt vmcnt(4)" ::: "memory");
    } else {
      asm volatile("s_waitcnt vmcnt(0)" ::: "memory");
    }
    MIDBAR();
    QUAD(af, bf23, 4, 2);
    ENDBAR();
    // ---- PH5: (t+1,q0) ----
    LDA_GRP(1, 0);
    LDB_GRP(1, 0, bf01);
    if (!last) stage(Abase, 0, kof2, AOFF(0, 0));
    MIDBAR();
    QUAD(af, bf01, 0, 0);
    ENDBAR();
    // ---- PH6: (t+1,q1) ----
    LDB_GRP(1, 2, bf23);
    if (!last) stage(Abase, 128, kof2, AOFF(0, 1));
    MIDBAR();
    QUAD(af, bf23, 0, 2);
    ENDBAR();
    // ---- PH7: (t+1,q2) ----
    LDA_GRP(1, 4);
    if (!last) stage(Bbase, 0, kof3, BOFF(1, 0));
    MIDBAR();
    QUAD(af, bf01, 4, 0);
    ENDBAR();
    // ---- PH8: (t+1,q3) ----
    if (!last) {
      stage(Bbase, 128, kof3, BOFF(1, 1));
      asm volatile("s_waitcnt vmcnt(4)" ::: "memory");
    }
    MIDBAR();
    QUAD(af, bf23, 4, 2);
    ENDBAR();
  }

  // ---- epilogue: C/D layout col = lane&15, row = (lane>>4)*4 + j ----
  const int r4 = (lane >> 4) * 4;
#pragma unroll
  for (int n = 0; n < 4; ++n) {
    const int cc = bcol + wc * 64 + n * 16 + l15;
    const float bv = bias[cc];
#pragma unroll
    for (int m = 0; m < 8; ++m)
#pragma unroll
      for (int j = 0; j < 4; ++j) {
        const int rr = brow + wr * 128 + m * 16 + r4 + j;
        C[(size_t)rr * N + cc] = acc[m][n][j] + bv;
      }
  }
}

// ---------------------------------------------------------------------------

extern "C" void kernel_launch(void* const* d_in, const int* in_sizes, int n_in,
                              void* d_out, int out_size, void* d_ws, size_t ws_size,
                              hipStream_t stream) {
  const float* x = (const float*)d_in[0];
  const float* wA = (const float*)d_in[1];
  const float* wB = (const float*)d_in[2];
  const float* bias = (const float*)d_in[3];
  const float* scaleA = (const float*)d_in[4];
  const float* scaleB = (const float*)d_in[5];
  float* out = (float*)d_out;

  char* ws = (char*)d_ws;
  _Float16* waT = (_Float16*)ws;                                  // 8 MB
  _Float16* wbs = (_Float16*)(ws + (size_t)RANK * IN_FEAT * 2);   // 8 MB
  _Float16* xp =
      (_Float16*)(ws + (size_t)RANK * IN_FEAT * 2 + (size_t)OUT_FEAT * RANK * 2);  // 16 MB
  _Float16* x16 = (_Float16*)(ws + (size_t)RANK * IN_FEAT * 2 +
                              (size_t)OUT_FEAT * RANK * 2 + (size_t)TOK * RANK * 2);  // 64 MB
  const size_t needed = (size_t)RANK * IN_FEAT * 2 + (size_t)OUT_FEAT * RANK * 2 +
                        (size_t)TOK * RANK * 2 + (size_t)TOK * IN_FEAT * 2;

  hipLaunchKernelGGL(sparsify_A_kernel, dim3((IN_FEAT * RANK / 4) / 256), dim3(256),
                     0, stream, wA, scaleA, waT);
  hipLaunchKernelGGL(sparsify_B_kernel, dim3((OUT_FEAT * RANK / 4) / 256), dim3(256),
                     0, stream, wB, scaleB, wbs);

  if (ws_size >= needed) {
    hipLaunchKernelGGL(cast_x_kernel, dim3((TOK * IN_FEAT / 8) / 256), dim3(256),
                       0, stream, x, x16);
    hipLaunchKernelGGL((gemm128<RANK, IN_FEAT, false, true>),
                       dim3(RANK / 128, TOK / 128), dim3(256), 0, stream,
                       (const void*)x16, waT, (void*)xp, nullptr);
  } else {
    hipLaunchKernelGGL((gemm128<RANK, IN_FEAT, true, true>),
                       dim3(RANK / 128, TOK / 128), dim3(256), 0, stream,
                       (const void*)x, waT, (void*)xp, nullptr);
  }

  // GEMM2: out(fp32) = x_proj @ wbs^T + bias — 8-phase 256^2 kernel
  (void)hipFuncSetAttribute(
      reinterpret_cast<const void*>(&gemm256<TOK, OUT_FEAT, RANK>),
      hipFuncAttributeMaxDynamicSharedMemorySize, 131072);
  hipLaunchKernelGGL((gemm256<TOK, OUT_FEAT, RANK>),
                     dim3(OUT_FEAT / 256, TOK / 256), dim3(512), 131072, stream,
                     xp, wbs, out, bias);
}

// Round 4
// 204.540 us; speedup vs baseline: 1.2857x; 1.0081x over previous
//
#include <hip/hip_runtime.h>

#define IN_FEAT 4096
#define OUT_FEAT 4096
#define RANK 1024
#define TOK 8192   // B*S = 4*2048

typedef _Float16 f16x8 __attribute__((ext_vector_type(8)));
typedef _Float16 f16x4 __attribute__((ext_vector_type(4)));
typedef float f32x4 __attribute__((ext_vector_type(4)));

#define GLD_LDS16(g, l)                                                         \
  __builtin_amdgcn_global_load_lds(                                             \
      (__attribute__((address_space(1))) const void*)(g),                       \
      (__attribute__((address_space(3))) void*)(l), 16, 0, 0)

#define MIDBAR()                                        \
  __builtin_amdgcn_s_barrier();                         \
  asm volatile("s_waitcnt lgkmcnt(0)" ::: "memory")
#define ENDBAR() __builtin_amdgcn_s_barrier()

// ---------------------------------------------------------------------------
// 2:4 soft-threshold sparsify, scale, cast to fp16.
// ---------------------------------------------------------------------------

__device__ __forceinline__ void soft24(const float4 g, float s,
                                       float& r0, float& r1, float& r2, float& r3) {
  const float m0 = fabsf(g.x), m1 = fabsf(g.y), m2 = fabsf(g.z), m3 = fabsf(g.w);
  const float lo1 = fminf(m0, m1), hi1 = fmaxf(m0, m1);
  const float lo2 = fminf(m2, m3), hi2 = fmaxf(m2, m3);
  const float t = fminf(fmaxf(lo1, lo2), fminf(hi1, hi2));  // 2nd smallest
  r0 = copysignf(fmaxf(m0 - t, 0.0f), g.x) * s;
  r1 = copysignf(fmaxf(m1 - t, 0.0f), g.y) * s;
  r2 = copysignf(fmaxf(m2 - t, 0.0f), g.z) * s;
  r3 = copysignf(fmaxf(m3 - t, 0.0f), g.w) * s;
}

__global__ __launch_bounds__(256) void sparsify_A_kernel(
    const float* __restrict__ wA, const float* __restrict__ scaleA,
    _Float16* __restrict__ waT) {
  const int idx = blockIdx.x * 256 + threadIdx.x;
  const int i = idx & (IN_FEAT - 1);
  const int jg = idx >> 12;
  const float4 g = *reinterpret_cast<const float4*>(wA + (size_t)i * RANK + jg * 4);
  const float s = scaleA[0];
  float r0, r1, r2, r3;
  soft24(g, s, r0, r1, r2, r3);
  const size_t base = (size_t)(jg * 4) * IN_FEAT + i;
  waT[base] = (_Float16)r0;
  waT[base + IN_FEAT] = (_Float16)r1;
  waT[base + 2 * IN_FEAT] = (_Float16)r2;
  waT[base + 3 * IN_FEAT] = (_Float16)r3;
}

__global__ __launch_bounds__(256) void sparsify_B_kernel(
    const float* __restrict__ wB, const float* __restrict__ scaleB,
    _Float16* __restrict__ wbs) {
  const int idx = blockIdx.x * 256 + threadIdx.x;
  const float4 g = *reinterpret_cast<const float4*>(wB + (size_t)idx * 4);
  const float s = scaleB[0];
  float r0, r1, r2, r3;
  soft24(g, s, r0, r1, r2, r3);
  f16x4 h;
  h[0] = (_Float16)r0; h[1] = (_Float16)r1; h[2] = (_Float16)r2; h[3] = (_Float16)r3;
  *reinterpret_cast<f16x4*>(wbs + (size_t)idx * 4) = h;
}

__global__ __launch_bounds__(256) void cast_x_kernel(
    const float* __restrict__ x, _Float16* __restrict__ x16) {
  const size_t i = ((size_t)blockIdx.x * 256 + threadIdx.x) * 8;
  const float4 f0 = *reinterpret_cast<const float4*>(x + i);
  const float4 f1 = *reinterpret_cast<const float4*>(x + i + 4);
  f16x8 h;
  h[0] = (_Float16)f0.x; h[1] = (_Float16)f0.y;
  h[2] = (_Float16)f0.z; h[3] = (_Float16)f0.w;
  h[4] = (_Float16)f1.x; h[5] = (_Float16)f1.y;
  h[6] = (_Float16)f1.z; h[7] = (_Float16)f1.w;
  *reinterpret_cast<f16x8*>(x16 + i) = h;
}

// ---------------------------------------------------------------------------
// 128x128-tile GEMM (verified R1/R2) — fallback path only.
// ---------------------------------------------------------------------------
template <int N, int K, bool A_F32, bool OUT_F16>
__global__ __launch_bounds__(256, 4) void gemm128(
    const void* __restrict__ Av, const _Float16* __restrict__ Bh,
    void* __restrict__ Cv, const float* __restrict__ bias) {
  __shared__ __attribute__((aligned(128))) char lds[32768];
  char* ldsA = lds;
  char* ldsB = lds + 16384;

  const int tid = threadIdx.x;
  const int lane = tid & 63;
  const int w = tid >> 6;
  const int wrow = (w >> 1) * 64;
  const int wcol = (w & 1) * 64;

  constexpr int GX = N / 128;
  const int nwg = GX * (TOK / 128);
  const int l = blockIdx.y * GX + blockIdx.x;
  const int wg = (l & 7) * (nwg >> 3) + (l >> 3);
  const int brow = (wg / GX) * 128;
  const int bcol = (wg % GX) * 128;

  f32x4 acc[4][4] = {};

  for (int k0 = 0; k0 < K; k0 += 64) {
    __syncthreads();
#pragma unroll
    for (int it = 0; it < 4; ++it) {
      const int c = it * 256 + tid;
      const int row = c >> 3;
      const int u = c & 7;
      const _Float16* gsrc =
          Bh + (size_t)(bcol + row) * K + k0 + ((u ^ (row & 7)) << 3);
      GLD_LDS16(gsrc, ldsB + c * 16);
    }
    if constexpr (A_F32) {
      const float* Af = (const float*)Av;
#pragma unroll
      for (int it = 0; it < 4; ++it) {
        const int c = it * 256 + tid;
        const int row = c >> 3;
        const int u = c & 7;
        const float* gsrc = Af + (size_t)(brow + row) * K + k0 + (u << 3);
        const float4 f0 = *reinterpret_cast<const float4*>(gsrc);
        const float4 f1 = *reinterpret_cast<const float4*>(gsrc + 4);
        f16x8 h;
        h[0] = (_Float16)f0.x; h[1] = (_Float16)f0.y;
        h[2] = (_Float16)f0.z; h[3] = (_Float16)f0.w;
        h[4] = (_Float16)f1.x; h[5] = (_Float16)f1.y;
        h[6] = (_Float16)f1.z; h[7] = (_Float16)f1.w;
        *reinterpret_cast<f16x8*>(ldsA + row * 128 + ((u ^ (row & 7)) << 4)) = h;
      }
    } else {
      const _Float16* Ah = (const _Float16*)Av;
#pragma unroll
      for (int it = 0; it < 4; ++it) {
        const int c = it * 256 + tid;
        const int row = c >> 3;
        const int u = c & 7;
        const _Float16* gsrc =
            Ah + (size_t)(brow + row) * K + k0 + ((u ^ (row & 7)) << 3);
        GLD_LDS16(gsrc, ldsA + c * 16);
      }
    }
    __syncthreads();
#pragma unroll
    for (int kk = 0; kk < 2; ++kk) {
      f16x8 af[4], bf[4];
#pragma unroll
      for (int m = 0; m < 4; ++m) {
        const int row = wrow + m * 16 + (lane & 15);
        const int u = (kk * 4 + (lane >> 4)) ^ (row & 7);
        af[m] = *reinterpret_cast<const f16x8*>(ldsA + row * 128 + u * 16);
      }
#pragma unroll
      for (int n = 0; n < 4; ++n) {
        const int row = wcol + n * 16 + (lane & 15);
        const int u = (kk * 4 + (lane >> 4)) ^ (row & 7);
        bf[n] = *reinterpret_cast<const f16x8*>(ldsB + row * 128 + u * 16);
      }
#pragma unroll
      for (int m = 0; m < 4; ++m)
#pragma unroll
        for (int n = 0; n < 4; ++n)
          acc[m][n] =
              __builtin_amdgcn_mfma_f32_16x16x32_f16(af[m], bf[n], acc[m][n], 0, 0, 0);
    }
  }

  const int r4 = (lane >> 4) * 4;
  const int cl = lane & 15;
  if constexpr (OUT_F16) {
    _Float16* C = (_Float16*)Cv;
#pragma unroll
    for (int m = 0; m < 4; ++m)
#pragma unroll
      for (int n = 0; n < 4; ++n)
#pragma unroll
        for (int j = 0; j < 4; ++j) {
          const int rr = brow + wrow + m * 16 + r4 + j;
          const int cc = bcol + wcol + n * 16 + cl;
          C[(size_t)rr * N + cc] = (_Float16)acc[m][n][j];
        }
  } else {
    float* C = (float*)Cv;
#pragma unroll
    for (int n = 0; n < 4; ++n) {
      const int cc = bcol + wcol + n * 16 + cl;
      const float bv = bias[cc];
#pragma unroll
      for (int m = 0; m < 4; ++m)
#pragma unroll
        for (int j = 0; j < 4; ++j) {
          const int rr = brow + wrow + m * 16 + r4 + j;
          C[(size_t)rr * N + cc] = acc[m][n][j] + bv;
        }
    }
  }
}

// ---------------------------------------------------------------------------
// GEMM1: 128(M)x256(N)-tile, 4-phase counted-vmcnt, C(f16) = A @ B^T.
// 8 waves (2M x 4N), per-wave 64x64, acc[4][4]. BK=64, 2 K-tiles/iter.
// LDS 96 KiB: A slots @0,16K (128x64 f16); B slots @32K,64K (256x64 f16).
// Phase roles per K-tile: pa reads A(m0-3)+B(n0-1) -> 16 MFMA; pb B(n2-3) -> 16.
// Stage: PH1 -> B(t+1), PH2 -> A(t+2), PH3 -> B(t+2), PH4 -> A(t+3).
// Every staged buffer's last read was >=1 ENDBAR earlier. vmcnt(2) at
// PH2/PH4 only (leaves newest A-stage in flight); vmcnt(0) only last iter.
// ---------------------------------------------------------------------------
template <int M, int N, int K>
__global__ __launch_bounds__(512, 2) void gemm1_k(
    const _Float16* __restrict__ A, const _Float16* __restrict__ B,
    _Float16* __restrict__ C) {
  extern __shared__ char lds[];

  const int tid = threadIdx.x;
  const int lane = tid & 63;
  const int w = tid >> 6;
  const int wr = w >> 2;   // 0..1 (M)
  const int wc = w & 3;    // 0..3 (N)
  const int l15 = lane & 15;
  const int ubase = lane >> 4;

  constexpr int GX = N / 256;           // 4
  constexpr int NWG = GX * (M / 128);   // 256
  const int l = blockIdx.y * GX + blockIdx.x;
  const int wg = (l & 7) * (NWG >> 3) + (l >> 3);
  const int brow = (wg / GX) * 128;
  const int bcol = (wg % GX) * 256;

  f32x4 acc[4][4] = {};
  f16x8 af[4][2], bf01[2][2], bf23[2][2];

  auto lda = [&](int slot) {
#pragma unroll
    for (int i = 0; i < 4; ++i)
#pragma unroll
      for (int ks = 0; ks < 2; ++ks) {
        const int row = wr * 64 + i * 16 + l15;
        const int u = (ks * 4 + ubase) ^ (row & 7);
        af[i][ks] =
            *reinterpret_cast<const f16x8*>(lds + slot * 16384 + row * 128 + u * 16);
      }
  };
  auto ldb = [&](int slot, int nbase, f16x8 (*dst)[2]) {
#pragma unroll
    for (int j = 0; j < 2; ++j)
#pragma unroll
      for (int ks = 0; ks < 2; ++ks) {
        const int row = wc * 64 + (nbase + j) * 16 + l15;
        const int u = (ks * 4 + ubase) ^ (row & 7);
        dst[j][ks] = *reinterpret_cast<const f16x8*>(lds + 32768 + slot * 32768 +
                                                     row * 128 + u * 16);
      }
  };
  auto stageA = [&](int kof, int slot) {
#pragma unroll
    for (int r = 0; r < 2; ++r) {
      const int c = r * 512 + tid;
      const int row = c >> 3;
      const int u = c & 7;
      GLD_LDS16(A + (size_t)(brow + row) * K + kof + ((u ^ (row & 7)) << 3),
                lds + slot * 16384 + c * 16);
    }
  };
  auto stageB = [&](int kof, int slot) {
#pragma unroll
    for (int r = 0; r < 4; ++r) {
      const int c = r * 512 + tid;
      const int row = c >> 3;
      const int u = c & 7;
      GLD_LDS16(B + (size_t)(bcol + row) * K + kof + ((u ^ (row & 7)) << 3),
                lds + 32768 + slot * 32768 + c * 16);
    }
  };

#define QUAD16(BF, NO)                                                         \
  __builtin_amdgcn_s_setprio(1);                                               \
  _Pragma("unroll") for (int ks = 0; ks < 2; ++ks)                             \
  _Pragma("unroll") for (int i = 0; i < 4; ++i)                                \
  _Pragma("unroll") for (int j = 0; j < 2; ++j)                                \
      acc[i][(NO) + j] = __builtin_amdgcn_mfma_f32_16x16x32_f16(               \
          af[i][ks], BF[j][ks], acc[i][(NO) + j], 0, 0, 0);                    \
  __builtin_amdgcn_s_setprio(0);

  constexpr int NT = K / 64;  // 64 K-tiles, 32 iters

  // prologue: A(0)->s0, B(0)->s0, A(1)->s1; leave A(1) in flight
  stageA(0, 0);
  stageB(0, 0);
  stageA(64, 1);
  asm volatile("s_waitcnt vmcnt(2)" ::: "memory");
  __builtin_amdgcn_s_barrier();

  for (int tt = 0; tt < NT; tt += 2) {
    const bool lastI = (tt + 2 >= NT);
    const int kB1 = tt * 64 + 64;
    const int kAB2 = tt * 64 + 128;
    const int kA3 = tt * 64 + 192;

    // PH1: tile t, n0-1
    lda(0);
    ldb(0, 0, bf01);
    stageB(kB1, 1);
    MIDBAR();
    QUAD16(bf01, 0);
    ENDBAR();
    // PH2: tile t, n2-3
    ldb(0, 2, bf23);
    if (!lastI) {
      stageA(kAB2, 0);
      asm volatile("s_waitcnt vmcnt(2)" ::: "memory");
    } else {
      asm volatile("s_waitcnt vmcnt(0)" ::: "memory");
    }
    MIDBAR();
    QUAD16(bf23, 2);
    ENDBAR();
    // PH3: tile t+1, n0-1
    lda(1);
    ldb(1, 0, bf01);
    if (!lastI) stageB(kAB2, 0);
    MIDBAR();
    QUAD16(bf01, 0);
    ENDBAR();
    // PH4: tile t+1, n2-3
    ldb(1, 2, bf23);
    if (!lastI) {
      stageA(kA3, 1);
      asm volatile("s_waitcnt vmcnt(2)" ::: "memory");
    }
    MIDBAR();
    QUAD16(bf23, 2);
    ENDBAR();
  }

  // epilogue: C/D layout col = lane&15, row = (lane>>4)*4 + j
  const int r4 = (lane >> 4) * 4;
#pragma unroll
  for (int m = 0; m < 4; ++m)
#pragma unroll
    for (int n = 0; n < 4; ++n)
#pragma unroll
      for (int j = 0; j < 4; ++j) {
        const int rr = brow + wr * 64 + m * 16 + r4 + j;
        const int cc = bcol + wc * 64 + n * 16 + l15;
        C[(size_t)rr * N + cc] = (_Float16)acc[m][n][j];
      }
#undef QUAD16
}

// ---------------------------------------------------------------------------
// 256x256 8-phase GEMM (verified R3) — GEMM2.
// ---------------------------------------------------------------------------
#define AOFF(s, h) (((s) * 2 + (h)) * 16384)
#define BOFF(s, h) (65536 + ((s) * 2 + (h)) * 16384)

#define QUAD(AF, BF, MO, NO)                                                   \
  __builtin_amdgcn_s_setprio(1);                                               \
  _Pragma("unroll") for (int ks = 0; ks < 2; ++ks)                             \
  _Pragma("unroll") for (int i = 0; i < 4; ++i)                                \
  _Pragma("unroll") for (int j = 0; j < 2; ++j)                                \
      acc[(MO) + i][(NO) + j] = __builtin_amdgcn_mfma_f32_16x16x32_f16(        \
          AF[i][ks], BF[j][ks], acc[(MO) + i][(NO) + j], 0, 0, 0);             \
  __builtin_amdgcn_s_setprio(0);

template <int M, int N, int K>
__global__ __launch_bounds__(512, 2) void gemm256(
    const _Float16* __restrict__ A, const _Float16* __restrict__ B,
    float* __restrict__ C, const float* __restrict__ bias) {
  extern __shared__ char lds[];

  const int tid = threadIdx.x;
  const int lane = tid & 63;
  const int w = tid >> 6;
  const int wr = w >> 2;
  const int wc = w & 3;
  const int l15 = lane & 15;
  const int ubase = lane >> 4;

  constexpr int GX = N / 256;
  constexpr int NWG = GX * (M / 256);
  const int l = blockIdx.y * GX + blockIdx.x;
  const int wg = (l & 7) * (NWG >> 3) + (l >> 3);
  const int brow = (wg / GX) * 256;
  const int bcol = (wg % GX) * 256;

  const _Float16* Abase = A + (size_t)brow * K;
  const _Float16* Bbase = B + (size_t)bcol * K;

  auto stage = [&](const _Float16* srcBase, int rowOff, int kof, int ldsOff) {
#pragma unroll
    for (int r = 0; r < 2; ++r) {
      const int c = r * 512 + tid;
      const int row = c >> 3;
      const int u = c & 7;
      const _Float16* g =
          srcBase + (size_t)(rowOff + row) * K + kof + ((u ^ (row & 7)) << 3);
      GLD_LDS16(g, lds + ldsOff + c * 16);
    }
  };

  f32x4 acc[8][4] = {};
  f16x8 af[4][2], bf01[2][2], bf23[2][2];

#define LDA_GRP(SLOT, MBASE)                                                   \
  _Pragma("unroll") for (int i = 0; i < 4; ++i)                                \
  _Pragma("unroll") for (int ks = 0; ks < 2; ++ks) {                           \
    const int row = ((MBASE) + i) * 16 + l15;                                  \
    const int u = (ks * 4 + ubase) ^ (row & 7);                                \
    af[i][ks] = *reinterpret_cast<const f16x8*>(                               \
        lds + AOFF(SLOT, wr) + row * 128 + u * 16);                            \
  }
#define LDB_GRP(SLOT, NBASE, DST)                                              \
  _Pragma("unroll") for (int j = 0; j < 2; ++j)                                \
  _Pragma("unroll") for (int ks = 0; ks < 2; ++ks) {                           \
    const int row = (wc & 1) * 64 + ((NBASE) + j) * 16 + l15;                  \
    const int u = (ks * 4 + ubase) ^ (row & 7);                                \
    DST[j][ks] = *reinterpret_cast<const f16x8*>(                              \
        lds + BOFF(SLOT, wc >> 1) + row * 128 + u * 16);                       \
  }

  constexpr int NT = K / 64;

  stage(Abase, 0, 0, AOFF(0, 0));
  stage(Abase, 128, 0, AOFF(0, 1));
  stage(Bbase, 0, 0, BOFF(0, 0));
  stage(Bbase, 128, 0, BOFF(0, 1));
  stage(Bbase, 0, 64, BOFF(1, 0));
  stage(Bbase, 128, 64, BOFF(1, 1));
  asm volatile("s_waitcnt vmcnt(4)" ::: "memory");
  __builtin_amdgcn_s_barrier();

  for (int tt = 0; tt < NT; tt += 2) {
    const bool last = (tt + 2 >= NT);
    const int kof1 = tt * 64 + 64;
    const int kof2 = tt * 64 + 128;
    const int kof3 = tt * 64 + 192;

    LDA_GRP(0, 0);
    LDB_GRP(0, 0, bf01);
    stage(Abase, 0, kof1, AOFF(1, 0));
    MIDBAR();
    QUAD(af, bf01, 0, 0);
    ENDBAR();

    LDB_GRP(0, 2, bf23);
    stage(Abase, 128, kof1, AOFF(1, 1));
    MIDBAR();
    QUAD(af, bf23, 0, 2);
    ENDBAR();

    LDA_GRP(0, 4);
    if (!last) stage(Bbase, 0, kof2, BOFF(0, 0));
    MIDBAR();
    QUAD(af, bf01, 4, 0);
    ENDBAR();

    if (!last) {
      stage(Bbase, 128, kof2, BOFF(0, 1));
      asm volatile("s_waitcnt vmcnt(4)" ::: "memory");
    } else {
      asm volatile("s_waitcnt vmcnt(0)" ::: "memory");
    }
    MIDBAR();
    QUAD(af, bf23, 4, 2);
    ENDBAR();

    LDA_GRP(1, 0);
    LDB_GRP(1, 0, bf01);
    if (!last) stage(Abase, 0, kof2, AOFF(0, 0));
    MIDBAR();
    QUAD(af, bf01, 0, 0);
    ENDBAR();

    LDB_GRP(1, 2, bf23);
    if (!last) stage(Abase, 128, kof2, AOFF(0, 1));
    MIDBAR();
    QUAD(af, bf23, 0, 2);
    ENDBAR();

    LDA_GRP(1, 4);
    if (!last) stage(Bbase, 0, kof3, BOFF(1, 0));
    MIDBAR();
    QUAD(af, bf01, 4, 0);
    ENDBAR();

    if (!last) {
      stage(Bbase, 128, kof3, BOFF(1, 1));
      asm volatile("s_waitcnt vmcnt(4)" ::: "memory");
    }
    MIDBAR();
    QUAD(af, bf23, 4, 2);
    ENDBAR();
  }

  const int r4 = (lane >> 4) * 4;
#pragma unroll
  for (int n = 0; n < 4; ++n) {
    const int cc = bcol + wc * 64 + n * 16 + l15;
    const float bv = bias[cc];
#pragma unroll
    for (int m = 0; m < 8; ++m)
#pragma unroll
      for (int j = 0; j < 4; ++j) {
        const int rr = brow + wr * 128 + m * 16 + r4 + j;
        C[(size_t)rr * N + cc] = acc[m][n][j] + bv;
      }
  }
}

// ---------------------------------------------------------------------------

extern "C" void kernel_launch(void* const* d_in, const int* in_sizes, int n_in,
                              void* d_out, int out_size, void* d_ws, size_t ws_size,
                              hipStream_t stream) {
  const float* x = (const float*)d_in[0];
  const float* wA = (const float*)d_in[1];
  const float* wB = (const float*)d_in[2];
  const float* bias = (const float*)d_in[3];
  const float* scaleA = (const float*)d_in[4];
  const float* scaleB = (const float*)d_in[5];
  float* out = (float*)d_out;

  char* ws = (char*)d_ws;
  _Float16* waT = (_Float16*)ws;                                  // 8 MB
  _Float16* wbs = (_Float16*)(ws + (size_t)RANK * IN_FEAT * 2);   // 8 MB
  _Float16* xp =
      (_Float16*)(ws + (size_t)RANK * IN_FEAT * 2 + (size_t)OUT_FEAT * RANK * 2);  // 16 MB
  _Float16* x16 = (_Float16*)(ws + (size_t)RANK * IN_FEAT * 2 +
                              (size_t)OUT_FEAT * RANK * 2 + (size_t)TOK * RANK * 2);  // 64 MB
  const size_t needed = (size_t)RANK * IN_FEAT * 2 + (size_t)OUT_FEAT * RANK * 2 +
                        (size_t)TOK * RANK * 2 + (size_t)TOK * IN_FEAT * 2;

  hipLaunchKernelGGL(sparsify_A_kernel, dim3((IN_FEAT * RANK / 4) / 256), dim3(256),
                     0, stream, wA, scaleA, waT);
  hipLaunchKernelGGL(sparsify_B_kernel, dim3((OUT_FEAT * RANK / 4) / 256), dim3(256),
                     0, stream, wB, scaleB, wbs);

  if (ws_size >= needed) {
    hipLaunchKernelGGL(cast_x_kernel, dim3((TOK * IN_FEAT / 8) / 256), dim3(256),
                       0, stream, x, x16);
    // GEMM1: xp(f16) = x16 @ waT^T — 128x256-tile 4-phase kernel
    (void)hipFuncSetAttribute(
        reinterpret_cast<const void*>(&gemm1_k<TOK, RANK, IN_FEAT>),
        hipFuncAttributeMaxDynamicSharedMemorySize, 98304);
    hipLaunchKernelGGL((gemm1_k<TOK, RANK, IN_FEAT>),
                       dim3(RANK / 256, TOK / 128), dim3(512), 98304, stream,
                       x16, waT, xp);
  } else {
    hipLaunchKernelGGL((gemm128<RANK, IN_FEAT, true, true>),
                       dim3(RANK / 128, TOK / 128), dim3(256), 0, stream,
                       (const void*)x, waT, (void*)xp, nullptr);
  }

  // GEMM2: out(fp32) = x_proj @ wbs^T + bias — 8-phase 256^2 kernel
  (void)hipFuncSetAttribute(
      reinterpret_cast<const void*>(&gemm256<TOK, OUT_FEAT, RANK>),
      hipFuncAttributeMaxDynamicSharedMemorySize, 131072);
  hipLaunchKernelGGL((gemm256<TOK, OUT_FEAT, RANK>),
                     dim3(OUT_FEAT / 256, TOK / 256), dim3(512), 131072, stream,
                     xp, wbs, out, bias);
}